// Round 4
// baseline (903.564 us; speedup 1.0000x reference)
//
#include <hip/hip_runtime.h>
#include <float.h>

// QueryPooling: x[B,L,C] f32, mask[B,L] i32, queries[K,C] f32 -> out[B,K,C] f32
// B=16 L=4096 C=1024 K=16. scale = C^-0.5 = 1/32.
#define NB 16
#define NL 4096
#define NC 1024
#define NK 16
#define SC2 0.04508422f  // (1/32)*log2(e)

typedef __attribute__((ext_vector_type(8))) short bf16x8;
typedef __attribute__((ext_vector_type(4))) float f32x4;

__device__ __forceinline__ float4 ld4(const float* p) { return *(const float4*)p; }

__device__ __forceinline__ void barrier_raw() {
  asm volatile("" ::: "memory");
  __builtin_amdgcn_s_barrier();
  asm volatile("" ::: "memory");
}

// ---------------------------------------------------------------------------
// Kernel 0: Q[16][1024] f32 -> Qh/Ql bf16 (hi/lo split, RNE both)
// ---------------------------------------------------------------------------
__global__ void qprep(const float* __restrict__ Q, unsigned short* __restrict__ Qh,
                      unsigned short* __restrict__ Ql) {
  const int i = (blockIdx.x * 256 + threadIdx.x) * 4;
  const float4 q = ld4(Q + i);
  const float qa[4] = {q.x, q.y, q.z, q.w};
  unsigned hh[4], ll[4];
#pragma unroll
  for (int u = 0; u < 4; ++u) {
    union { float f; unsigned v; } z; z.f = qa[u];
    const unsigned rr = z.v + 0x7FFFu + ((z.v >> 16) & 1u);
    hh[u] = rr >> 16;
    union { unsigned v; float f; } hf; hf.v = rr & 0xFFFF0000u;
    union { float f; unsigned v; } z2; z2.f = qa[u] - hf.f;
    ll[u] = (z2.v + 0x7FFFu + ((z2.v >> 16) & 1u)) >> 16;
  }
  uint2 ph, pl;
  ph.x = hh[0] | (hh[1] << 16); ph.y = hh[2] | (hh[3] << 16);
  pl.x = ll[0] | (ll[1] << 16); pl.y = ll[2] | (ll[3] << 16);
  *(uint2*)(Qh + i) = ph;
  *(uint2*)(Ql + i) = pl;
}

// ---------------------------------------------------------------------------
// Kernel 1: fused scores(MFMA bf16-split) + online softmax + PV(f32 VALU).
// grid 256 (1 block/CU), 512 threads (8 waves). Slab = 256 rows, 16 tiles
// of 16 rows. X staged reg->LDS with f32->bf16 hi/lo conversion (T14:
// loads issued phase 1, converted phase 4; raw barriers never drain vmcnt).
//
// Per tile: [1] issue next-tile global loads (8 dwordx4/thread)
//           [2] scores: wave w does K-range 128 (4 K-steps x 3 MFMA),
//               partial S[16q][16r] -> Sp[w]        | lgkm0 + barrier B
//           [3] all waves: reduce Sp over w, per-lane online softmax
//               (lane holds q=g*4+j, r=lane&15; r-reduce = shfl_xor 1/2/4/8),
//               wave 0 writes W[r][q], aS[q]        | lgkm0 + barrier C
//           [4] rescale o by aS; PV: wave w owns c-range [w*128,+128),
//               2 c/lane, reads X hi+lo (b32, stride-1) + W broadcast;
//               then convert staged regs -> buf^1   | lgkm0 + barrier A
// LDS: Xh/Xl [2][16][1032] bf16 (132KB, pad->bank-uniform frags) + Sp 8KB
//      + W 1KB + misc = ~142KB -> 1 block/CU, 8 waves.
// VGPR: stage 32 + Qfrags 32 + o 32 + state ~12 + temps -> ~150, cap 256.
// ---------------------------------------------------------------------------
__global__ __launch_bounds__(512, 2)
void qpool_partial(const float* __restrict__ X, const int* __restrict__ Mk,
                   const unsigned short* __restrict__ Qhg,
                   const unsigned short* __restrict__ Qlg,
                   float* __restrict__ Op, float* __restrict__ MSp) {
  constexpr int ROWS = 256;
  constexpr int NT   = 16;
  constexpr int LDX  = 1032;   // padded row length in bf16 units

  __shared__ unsigned short Xh[2][16 * LDX];
  __shared__ unsigned short Xl[2][16 * LDX];
  __shared__ float Sp[8 * 256];   // [w][r][q]
  __shared__ float Wl[256];       // [r][q]
  __shared__ float aS[16];
  __shared__ int   Msl[ROWS];

  const int tid  = threadIdx.x;
  const int lane = tid & 63;
  const int w    = tid >> 6;
  const int r16  = lane & 15;
  const int g    = lane >> 4;
  const int blk  = blockIdx.x;
  const int b    = blk >> 4;
  const int l0   = (blk & 15) * ROWS;

  const float* Xb = X + (size_t)b * NL * NC + (size_t)l0 * NC;

  // ---- Q fragments into registers: wave w -> K-steps w*4..w*4+3 ----
  bf16x8 qfh[4], qfl[4];
#pragma unroll
  for (int s = 0; s < 4; ++s) {
    const int off = r16 * NC + (w * 4 + s) * 32 + g * 8;
    qfh[s] = *(const bf16x8*)(Qhg + off);
    qfl[s] = *(const bf16x8*)(Qlg + off);
  }

  if (tid < ROWS) Msl[tid] = Mk[(size_t)b * NL + l0 + tid];

  float o0[16], o1[16];
#pragma unroll
  for (int q = 0; q < 16; ++q) { o0[q] = 0.f; o1[q] = 0.f; }
  float m_run[4], s_run[4];
#pragma unroll
  for (int j = 0; j < 4; ++j) { m_run[j] = -FLT_MAX; s_run[j] = 0.f; }

  float4 st[8];

  // conversion: st regs -> Xh/Xl[nb], thread owns float4s f = j*512+tid
  auto convert_write = [&](int nb) {
#pragma unroll
    for (int j = 0; j < 8; ++j) {
      const int f = j * 512 + tid;
      const int r = f >> 8, cq = f & 255;
      const float xa[4] = {st[j].x, st[j].y, st[j].z, st[j].w};
      unsigned hh[4], ll[4];
#pragma unroll
      for (int u = 0; u < 4; ++u) {
        union { float f; unsigned v; } z; z.f = xa[u];
        const unsigned rr = z.v + 0x7FFFu + ((z.v >> 16) & 1u);
        hh[u] = rr >> 16;
        union { unsigned v; float f; } hf; hf.v = rr & 0xFFFF0000u;
        union { float f; unsigned v; } z2; z2.f = xa[u] - hf.f;
        ll[u] = (z2.v + 0x7FFFu + ((z2.v >> 16) & 1u)) >> 16;
      }
      uint2 ph, pl;
      ph.x = hh[0] | (hh[1] << 16); ph.y = hh[2] | (hh[3] << 16);
      pl.x = ll[0] | (ll[1] << 16); pl.y = ll[2] | (ll[3] << 16);
      *(uint2*)&Xh[nb][r * LDX + cq * 4] = ph;
      *(uint2*)&Xl[nb][r * LDX + cq * 4] = pl;
    }
  };

  // ---- prologue: stage + convert tile 0 ----
#pragma unroll
  for (int j = 0; j < 8; ++j) st[j] = ld4(Xb + (size_t)(j * 512 + tid) * 4);
  convert_write(0);
  asm volatile("s_waitcnt lgkmcnt(0)" ::: "memory");
  barrier_raw();

  for (int t = 0; t < NT; ++t) {
    const int buf = t & 1;
    const unsigned short* Xhc = &Xh[buf][0];
    const unsigned short* Xlc = &Xl[buf][0];

    // [1] issue next-tile loads (in flight across barriers B, C)
    if (t + 1 < NT) {
      const float* Xn = Xb + (size_t)(t + 1) * 16 * NC;
#pragma unroll
      for (int j = 0; j < 8; ++j) st[j] = ld4(Xn + (size_t)(j * 512 + tid) * 4);
    }

    // [2] scores: partial S over this wave's K-range
    f32x4 sacc = {0.f, 0.f, 0.f, 0.f};
#pragma unroll
    for (int s = 0; s < 4; ++s) {
      const int co = (w * 4 + s) * 32 + g * 8;
      const bf16x8 xh = *(const bf16x8*)&Xhc[r16 * LDX + co];
      const bf16x8 xl = *(const bf16x8*)&Xlc[r16 * LDX + co];
      sacc = __builtin_amdgcn_mfma_f32_16x16x32_bf16(qfh[s], xh, sacc, 0, 0, 0);
      sacc = __builtin_amdgcn_mfma_f32_16x16x32_bf16(qfh[s], xl, sacc, 0, 0, 0);
      sacc = __builtin_amdgcn_mfma_f32_16x16x32_bf16(qfl[s], xh, sacc, 0, 0, 0);
    }
    *(f32x4*)&Sp[w * 256 + r16 * 16 + g * 4] = sacc;
    asm volatile("s_waitcnt lgkmcnt(0)" ::: "memory");
    barrier_raw();   // B: partials visible

    // [3] reduce + online softmax (all waves identical; lane = (q=g*4+j, r=r16))
    float sred[4] = {0.f, 0.f, 0.f, 0.f};
#pragma unroll
    for (int ww = 0; ww < 8; ++ww) {
      const f32x4 p = *(const f32x4*)&Sp[ww * 256 + r16 * 16 + g * 4];
      sred[0] += p[0]; sred[1] += p[1]; sred[2] += p[2]; sred[3] += p[3];
    }
    const int mskr = Msl[t * 16 + r16];
    float e4[4], al4[4];
#pragma unroll
    for (int j = 0; j < 4; ++j) {
      float mx = mskr ? sred[j] : -FLT_MAX;
      mx = fmaxf(mx, __shfl_xor(mx, 1, 64));
      mx = fmaxf(mx, __shfl_xor(mx, 2, 64));
      mx = fmaxf(mx, __shfl_xor(mx, 4, 64));
      mx = fmaxf(mx, __shfl_xor(mx, 8, 64));
      const float mnew = fmaxf(m_run[j], mx);
      const float e = mskr ? exp2f((sred[j] - mnew) * SC2) : 0.f;
      float cs = e;
      cs += __shfl_xor(cs, 1, 64);
      cs += __shfl_xor(cs, 2, 64);
      cs += __shfl_xor(cs, 4, 64);
      cs += __shfl_xor(cs, 8, 64);
      al4[j] = exp2f((m_run[j] - mnew) * SC2);   // ==1 when unchanged
      s_run[j] = s_run[j] * al4[j] + cs;
      m_run[j] = mnew;
      e4[j] = e;
    }
    if (w == 0) {
      *(float4*)&Wl[r16 * 16 + g * 4] = make_float4(e4[0], e4[1], e4[2], e4[3]);
      if (r16 == 0) *(float4*)&aS[g * 4] = make_float4(al4[0], al4[1], al4[2], al4[3]);
    }
    asm volatile("s_waitcnt lgkmcnt(0)" ::: "memory");
    barrier_raw();   // C: W/aS visible

    // [4a] rescale + PV (wave w owns c-range [w*128, +128), 2 c per lane)
    float aq[16];
#pragma unroll
    for (int qg = 0; qg < 4; ++qg) {
      const float4 a = *(const float4*)&aS[qg * 4];
      aq[qg * 4] = a.x; aq[qg * 4 + 1] = a.y; aq[qg * 4 + 2] = a.z; aq[qg * 4 + 3] = a.w;
    }
#pragma unroll
    for (int q = 0; q < 16; ++q) { o0[q] *= aq[q]; o1[q] *= aq[q]; }

    const int cidx = w * 128 + lane * 2;   // bf16/float column index
#pragma unroll
    for (int r = 0; r < 16; ++r) {
      const unsigned hp = *(const unsigned*)&Xhc[r * LDX + cidx];
      const unsigned lp = *(const unsigned*)&Xlc[r * LDX + cidx];
      union { unsigned v; float f; } u0, u1, u2, u3;
      u0.v = hp << 16;          u1.v = lp << 16;
      u2.v = hp & 0xFFFF0000u;  u3.v = lp & 0xFFFF0000u;
      const float x0 = u0.f + u1.f;
      const float x1 = u2.f + u3.f;
      const float4 wv0 = *(const float4*)&Wl[r * 16 + 0];
      const float4 wv1 = *(const float4*)&Wl[r * 16 + 4];
      const float4 wv2 = *(const float4*)&Wl[r * 16 + 8];
      const float4 wv3 = *(const float4*)&Wl[r * 16 + 12];
      const float wq[16] = {wv0.x, wv0.y, wv0.z, wv0.w, wv1.x, wv1.y, wv1.z, wv1.w,
                            wv2.x, wv2.y, wv2.z, wv2.w, wv3.x, wv3.y, wv3.z, wv3.w};
#pragma unroll
      for (int q = 0; q < 16; ++q) {
        o0[q] = fmaf(wq[q], x0, o0[q]);
        o1[q] = fmaf(wq[q], x1, o1[q]);
      }
    }

    // [4b] convert staged regs -> buf^1 (the only vmcnt wait, compiler-inserted)
    if (t + 1 < NT) convert_write(buf ^ 1);
    asm volatile("s_waitcnt lgkmcnt(0)" ::: "memory");
    barrier_raw();   // A: buf^1 staged, buf free
  }

  // ---- epilogue ----
  float* Ob = Op + (size_t)blk * NK * NC;
  const int cidx = w * 128 + lane * 2;
#pragma unroll
  for (int q = 0; q < 16; ++q)
    *(float2*)(Ob + (size_t)q * NC + cidx) = make_float2(o0[q], o1[q]);
  if (w == 0 && r16 == 0) {
#pragma unroll
    for (int j = 0; j < 4; ++j) {
      const int q = g * 4 + j;
      MSp[(blk * 16 + q) * 2]     = m_run[j];
      MSp[(blk * 16 + q) * 2 + 1] = s_run[j];
    }
  }
}

// ---------------------------------------------------------------------------
// Kernel 2: merge 16 slab partials per (b,k), max-rescale + normalize.
// All-masked rows -> denom 0 -> zeros (matches reference valid-branch).
// ---------------------------------------------------------------------------
__global__ __launch_bounds__(256, 2)
void qpool_combine(const float* __restrict__ Op, const float* __restrict__ MSp,
                   float* __restrict__ Out) {
  const int bk = blockIdx.x;
  const int b = bk >> 4, k = bk & 15;
  const int tid = threadIdx.x;

  float m[16], s[16], f[16];
  float M = -FLT_MAX;
#pragma unroll
  for (int lb = 0; lb < 16; ++lb) {
    m[lb] = MSp[((b * 16 + lb) * 16 + k) * 2];
    s[lb] = MSp[((b * 16 + lb) * 16 + k) * 2 + 1];
    M = fmaxf(M, m[lb]);
  }
  float denom = 0.f;
#pragma unroll
  for (int lb = 0; lb < 16; ++lb) {
    f[lb] = exp2f((m[lb] - M) * SC2);
    denom += s[lb] * f[lb];
  }
  float4 acc = make_float4(0.f, 0.f, 0.f, 0.f);
#pragma unroll
  for (int lb = 0; lb < 16; ++lb) {
    const float4 v = ld4(Op + ((size_t)(b * 16 + lb) * 16 + k) * NC + tid * 4);
    acc.x = fmaf(f[lb], v.x, acc.x);
    acc.y = fmaf(f[lb], v.y, acc.y);
    acc.z = fmaf(f[lb], v.z, acc.z);
    acc.w = fmaf(f[lb], v.w, acc.w);
  }
  const float inv = denom > 0.f ? 1.f / denom : 0.f;
  acc.x *= inv; acc.y *= inv; acc.z *= inv; acc.w *= inv;
  *(float4*)(Out + (size_t)bk * NC + tid * 4) = acc;
}

extern "C" void kernel_launch(void* const* d_in, const int* in_sizes, int n_in,
                              void* d_out, int out_size, void* d_ws, size_t ws_size,
                              hipStream_t stream) {
  const float* X  = (const float*)d_in[0];
  const int*   Mk = (const int*)d_in[1];
  const float* Q  = (const float*)d_in[2];
  float* Out = (float*)d_out;

  float* Op  = (float*)d_ws;                       // 256*16*1024 f32 = 16 MB
  float* MSp = Op + (size_t)256 * NK * NC;         // 8192 f32
  unsigned short* Qh = (unsigned short*)(MSp + 8192);
  unsigned short* Ql = Qh + NK * NC;

  qprep<<<16, 256, 0, stream>>>(Q, Qh, Ql);
  qpool_partial<<<256, 512, 0, stream>>>(X, Mk, Qh, Ql, Op, MSp);
  qpool_combine<<<256, 256, 0, stream>>>(Op, MSp, Out);
}

// Round 7
// 901.530 us; speedup vs baseline: 1.0023x; 1.0023x over previous
//
#include <hip/hip_runtime.h>
#include <float.h>

// QueryPooling: x[B,L,C] f32, mask[B,L] i32, queries[K,C] f32 -> out[B,K,C] f32
// B=16 L=4096 C=1024 K=16. scale = C^-0.5 = 1/32.
#define NB 16
#define NL 4096
#define NC 1024
#define NK 16
#define SC2 0.04508422f  // (1/32)*log2(e)

typedef __attribute__((ext_vector_type(8))) short bf16x8;
typedef __attribute__((ext_vector_type(4))) float f32x4;

__device__ __forceinline__ float4 ld4(const float* p) { return *(const float4*)p; }

__device__ __forceinline__ void barrier_raw() {
  asm volatile("" ::: "memory");
  __builtin_amdgcn_s_barrier();
  asm volatile("" ::: "memory");
}

// ---------------------------------------------------------------------------
// Kernel 0: Q[16][1024] f32 -> Qh/Ql bf16 (hi/lo split, RNE both)
// ---------------------------------------------------------------------------
__global__ void qprep(const float* __restrict__ Q, unsigned short* __restrict__ Qh,
                      unsigned short* __restrict__ Ql) {
  const int i = (blockIdx.x * 256 + threadIdx.x) * 4;
  const float4 q = ld4(Q + i);
  const float qa[4] = {q.x, q.y, q.z, q.w};
  unsigned hh[4], ll[4];
#pragma unroll
  for (int u = 0; u < 4; ++u) {
    union { float f; unsigned v; } z; z.f = qa[u];
    const unsigned rr = z.v + 0x7FFFu + ((z.v >> 16) & 1u);
    hh[u] = rr >> 16;
    union { unsigned v; float f; } hf; hf.v = rr & 0xFFFF0000u;
    union { float f; unsigned v; } z2; z2.f = qa[u] - hf.f;
    ll[u] = (z2.v + 0x7FFFu + ((z2.v >> 16) & 1u)) >> 16;
  }
  uint2 ph, pl;
  ph.x = hh[0] | (hh[1] << 16); ph.y = hh[2] | (hh[3] << 16);
  pl.x = ll[0] | (ll[1] << 16); pl.y = ll[2] | (ll[3] << 16);
  *(uint2*)(Qh + i) = ph;
  *(uint2*)(Ql + i) = pl;
}

// ---------------------------------------------------------------------------
// Kernel 1: fused scores(MFMA bf16-split) + online softmax + PV(f32 VALU).
// grid 256 (1 block/CU), 512 threads (8 waves). Slab = 256 rows, 16 tiles
// of 16 rows. X staged reg->LDS with f32->bf16 hi/lo conversion (T14:
// loads issued phase 1, converted phase 4; raw barriers never drain vmcnt).
//
// __launch_bounds__(512, 1): ROUND-5 FIX. Empirically arg=2 imposes a
// 128-VGPR cap (R2-R4 all spilled: R4 showed 1.5 GB scratch writes);
// arg=1 gives the 256 cap. Demand ~180 VGPR -> no spill. LDS (143 KB)
// limits to 1 block/CU anyway, so nothing is lost.
//
// Per tile: [1] issue next-tile global loads (8 dwordx4/thread)
//           [2] scores: wave w does K-range 128 (4 K-steps x 3 MFMA),
//               partial S -> Sp[w] (stride-17 rows, 4xb32: 2-way banks)
//           [3] all waves: reduce Sp over w, per-lane online softmax
//               (lane holds q=g*4+j, r=lane&15; r-reduce = shfl_xor 1/2/4/8),
//               wave 0 writes W[r][q], aS[q]        | lgkm0 + barrier C
//           [4] rescale o by aS; PV: wave w owns c-range [w*128,+128),
//               2 c/lane, reads X hi+lo (b32, stride-1, 2-way) + W broadcast;
//               then convert staged regs -> buf^1   | lgkm0 + barrier A
// LDS: Xh/Xl [2][16][1032] bf16 (129KB, row stride 2064B -> b128 fragment
// reads land distinct bank-quads per 8-lane group) + Sp 8.5KB + W 1KB
// + misc = ~143KB -> 1 block/CU, 8 waves.
// ---------------------------------------------------------------------------
__global__ __launch_bounds__(512, 1)
void qpool_partial(const float* __restrict__ X, const int* __restrict__ Mk,
                   const unsigned short* __restrict__ Qhg,
                   const unsigned short* __restrict__ Qlg,
                   float* __restrict__ Op, float* __restrict__ MSp) {
  constexpr int ROWS = 256;
  constexpr int NT   = 16;
  constexpr int LDX  = 1032;   // padded row length in bf16 units
  constexpr int SPS  = 17;     // Sp row stride (dwords): 17r+4g+j mod 32 = 2-way

  __shared__ unsigned short Xh[2][16 * LDX];
  __shared__ unsigned short Xl[2][16 * LDX];
  __shared__ float Sp[8 * 16 * SPS];   // [w][r][q] padded
  __shared__ float Wl[256];            // [r][q]
  __shared__ float aS[16];
  __shared__ int   Msl[ROWS];

  const int tid  = threadIdx.x;
  const int lane = tid & 63;
  const int w    = tid >> 6;
  const int r16  = lane & 15;
  const int g    = lane >> 4;
  const int blk  = blockIdx.x;
  const int b    = blk >> 4;
  const int l0   = (blk & 15) * ROWS;

  const float* Xb = X + (size_t)b * NL * NC + (size_t)l0 * NC;

  // ---- Q fragments into registers: wave w -> K-steps w*4..w*4+3 ----
  bf16x8 qfh[4], qfl[4];
#pragma unroll
  for (int s = 0; s < 4; ++s) {
    const int off = r16 * NC + (w * 4 + s) * 32 + g * 8;
    qfh[s] = *(const bf16x8*)(Qhg + off);
    qfl[s] = *(const bf16x8*)(Qlg + off);
  }

  if (tid < ROWS) Msl[tid] = Mk[(size_t)b * NL + l0 + tid];

  float o0[16], o1[16];
#pragma unroll
  for (int q = 0; q < 16; ++q) { o0[q] = 0.f; o1[q] = 0.f; }
  float m_run[4], s_run[4];
#pragma unroll
  for (int j = 0; j < 4; ++j) { m_run[j] = -FLT_MAX; s_run[j] = 0.f; }

  float4 st[8];

  // conversion: st regs -> Xh/Xl[nb], thread owns float4s f = j*512+tid
  auto convert_write = [&](int nb) {
#pragma unroll
    for (int j = 0; j < 8; ++j) {
      const int f = j * 512 + tid;
      const int r = f >> 8, cq = f & 255;
      const float xa[4] = {st[j].x, st[j].y, st[j].z, st[j].w};
      unsigned hh[4], ll[4];
#pragma unroll
      for (int u = 0; u < 4; ++u) {
        union { float f; unsigned v; } z; z.f = xa[u];
        const unsigned rr = z.v + 0x7FFFu + ((z.v >> 16) & 1u);
        hh[u] = rr >> 16;
        union { unsigned v; float f; } hf; hf.v = rr & 0xFFFF0000u;
        union { float f; unsigned v; } z2; z2.f = xa[u] - hf.f;
        ll[u] = (z2.v + 0x7FFFu + ((z2.v >> 16) & 1u)) >> 16;
      }
      uint2 ph, pl;
      ph.x = hh[0] | (hh[1] << 16); ph.y = hh[2] | (hh[3] << 16);
      pl.x = ll[0] | (ll[1] << 16); pl.y = ll[2] | (ll[3] << 16);
      *(uint2*)&Xh[nb][r * LDX + cq * 4] = ph;
      *(uint2*)&Xl[nb][r * LDX + cq * 4] = pl;
    }
  };

  // ---- prologue: stage + convert tile 0 ----
#pragma unroll
  for (int j = 0; j < 8; ++j) st[j] = ld4(Xb + (size_t)(j * 512 + tid) * 4);
  convert_write(0);
  asm volatile("s_waitcnt lgkmcnt(0)" ::: "memory");
  barrier_raw();

  for (int t = 0; t < NT; ++t) {
    const int buf = t & 1;
    const unsigned short* Xhc = &Xh[buf][0];
    const unsigned short* Xlc = &Xl[buf][0];

    // [1] issue next-tile loads (in flight across barriers B, C)
    if (t + 1 < NT) {
      const float* Xn = Xb + (size_t)(t + 1) * 16 * NC;
#pragma unroll
      for (int j = 0; j < 8; ++j) st[j] = ld4(Xn + (size_t)(j * 512 + tid) * 4);
    }

    // [2] scores: partial S over this wave's K-range
    f32x4 sacc = {0.f, 0.f, 0.f, 0.f};
#pragma unroll
    for (int s = 0; s < 4; ++s) {
      const int co = (w * 4 + s) * 32 + g * 8;
      const bf16x8 xh = *(const bf16x8*)&Xhc[r16 * LDX + co];
      const bf16x8 xl = *(const bf16x8*)&Xlc[r16 * LDX + co];
      sacc = __builtin_amdgcn_mfma_f32_16x16x32_bf16(qfh[s], xh, sacc, 0, 0, 0);
      sacc = __builtin_amdgcn_mfma_f32_16x16x32_bf16(qfh[s], xl, sacc, 0, 0, 0);
      sacc = __builtin_amdgcn_mfma_f32_16x16x32_bf16(qfl[s], xh, sacc, 0, 0, 0);
    }
    // sacc[reg] = S[q=g*4+reg][r=r16]; store 4xb32 into padded Sp (2-way banks)
#pragma unroll
    for (int reg = 0; reg < 4; ++reg)
      Sp[w * 16 * SPS + r16 * SPS + g * 4 + reg] = sacc[reg];
    asm volatile("s_waitcnt lgkmcnt(0)" ::: "memory");
    barrier_raw();   // B: partials visible

    // [3] reduce + online softmax (all waves identical; lane = (q=g*4+j, r=r16))
    float sred[4] = {0.f, 0.f, 0.f, 0.f};
#pragma unroll
    for (int ww = 0; ww < 8; ++ww) {
#pragma unroll
      for (int reg = 0; reg < 4; ++reg)
        sred[reg] += Sp[ww * 16 * SPS + r16 * SPS + g * 4 + reg];
    }
    const int mskr = Msl[t * 16 + r16];
    float e4[4], al4[4];
#pragma unroll
    for (int j = 0; j < 4; ++j) {
      float mx = mskr ? sred[j] : -FLT_MAX;
      mx = fmaxf(mx, __shfl_xor(mx, 1, 64));
      mx = fmaxf(mx, __shfl_xor(mx, 2, 64));
      mx = fmaxf(mx, __shfl_xor(mx, 4, 64));
      mx = fmaxf(mx, __shfl_xor(mx, 8, 64));
      const float mnew = fmaxf(m_run[j], mx);
      const float e = mskr ? exp2f((sred[j] - mnew) * SC2) : 0.f;
      float cs = e;
      cs += __shfl_xor(cs, 1, 64);
      cs += __shfl_xor(cs, 2, 64);
      cs += __shfl_xor(cs, 4, 64);
      cs += __shfl_xor(cs, 8, 64);
      al4[j] = exp2f((m_run[j] - mnew) * SC2);   // ==1 when unchanged
      s_run[j] = s_run[j] * al4[j] + cs;
      m_run[j] = mnew;
      e4[j] = e;
    }
    if (w == 0) {
      *(float4*)&Wl[r16 * 16 + g * 4] = make_float4(e4[0], e4[1], e4[2], e4[3]);
      if (r16 == 0) *(float4*)&aS[g * 4] = make_float4(al4[0], al4[1], al4[2], al4[3]);
    }
    asm volatile("s_waitcnt lgkmcnt(0)" ::: "memory");
    barrier_raw();   // C: W/aS visible

    // [4a] rescale + PV (wave w owns c-range [w*128, +128), 2 c per lane)
    float aq[16];
#pragma unroll
    for (int qg = 0; qg < 4; ++qg) {
      const float4 a = *(const float4*)&aS[qg * 4];
      aq[qg * 4] = a.x; aq[qg * 4 + 1] = a.y; aq[qg * 4 + 2] = a.z; aq[qg * 4 + 3] = a.w;
    }
#pragma unroll
    for (int q = 0; q < 16; ++q) { o0[q] *= aq[q]; o1[q] *= aq[q]; }

    const int cidx = w * 128 + lane * 2;   // bf16/float column index
#pragma unroll
    for (int r = 0; r < 16; ++r) {
      const unsigned hp = *(const unsigned*)&Xhc[r * LDX + cidx];
      const unsigned lp = *(const unsigned*)&Xlc[r * LDX + cidx];
      union { unsigned v; float f; } u0, u1, u2, u3;
      u0.v = hp << 16;          u1.v = lp << 16;
      u2.v = hp & 0xFFFF0000u;  u3.v = lp & 0xFFFF0000u;
      const float x0 = u0.f + u1.f;
      const float x1 = u2.f + u3.f;
      const float4 wv0 = *(const float4*)&Wl[r * 16 + 0];
      const float4 wv1 = *(const float4*)&Wl[r * 16 + 4];
      const float4 wv2 = *(const float4*)&Wl[r * 16 + 8];
      const float4 wv3 = *(const float4*)&Wl[r * 16 + 12];
      const float wq[16] = {wv0.x, wv0.y, wv0.z, wv0.w, wv1.x, wv1.y, wv1.z, wv1.w,
                            wv2.x, wv2.y, wv2.z, wv2.w, wv3.x, wv3.y, wv3.z, wv3.w};
#pragma unroll
      for (int q = 0; q < 16; ++q) {
        o0[q] = fmaf(wq[q], x0, o0[q]);
        o1[q] = fmaf(wq[q], x1, o1[q]);
      }
    }

    // [4b] convert staged regs -> buf^1 (the only vmcnt wait, compiler-inserted)
    if (t + 1 < NT) convert_write(buf ^ 1);
    asm volatile("s_waitcnt lgkmcnt(0)" ::: "memory");
    barrier_raw();   // A: buf^1 staged, buf free
  }

  // ---- epilogue ----
  float* Ob = Op + (size_t)blk * NK * NC;
  const int cidx = w * 128 + lane * 2;
#pragma unroll
  for (int q = 0; q < 16; ++q)
    *(float2*)(Ob + (size_t)q * NC + cidx) = make_float2(o0[q], o1[q]);
  if (w == 0 && r16 == 0) {
#pragma unroll
    for (int j = 0; j < 4; ++j) {
      const int q = g * 4 + j;
      MSp[(blk * 16 + q) * 2]     = m_run[j];
      MSp[(blk * 16 + q) * 2 + 1] = s_run[j];
    }
  }
}

// ---------------------------------------------------------------------------
// Kernel 2: merge 16 slab partials per (b,k), max-rescale + normalize.
// All-masked rows -> denom 0 -> zeros (matches reference valid-branch).
// ---------------------------------------------------------------------------
__global__ __launch_bounds__(256, 1)
void qpool_combine(const float* __restrict__ Op, const float* __restrict__ MSp,
                   float* __restrict__ Out) {
  const int bk = blockIdx.x;
  const int b = bk >> 4, k = bk & 15;
  const int tid = threadIdx.x;

  float m[16], s[16], f[16];
  float M = -FLT_MAX;
#pragma unroll
  for (int lb = 0; lb < 16; ++lb) {
    m[lb] = MSp[((b * 16 + lb) * 16 + k) * 2];
    s[lb] = MSp[((b * 16 + lb) * 16 + k) * 2 + 1];
    M = fmaxf(M, m[lb]);
  }
  float denom = 0.f;
#pragma unroll
  for (int lb = 0; lb < 16; ++lb) {
    f[lb] = exp2f((m[lb] - M) * SC2);
    denom += s[lb] * f[lb];
  }
  float4 acc = make_float4(0.f, 0.f, 0.f, 0.f);
#pragma unroll
  for (int lb = 0; lb < 16; ++lb) {
    const float4 v = ld4(Op + ((size_t)(b * 16 + lb) * 16 + k) * NC + tid * 4);
    acc.x = fmaf(f[lb], v.x, acc.x);
    acc.y = fmaf(f[lb], v.y, acc.y);
    acc.z = fmaf(f[lb], v.z, acc.z);
    acc.w = fmaf(f[lb], v.w, acc.w);
  }
  const float inv = denom > 0.f ? 1.f / denom : 0.f;
  acc.x *= inv; acc.y *= inv; acc.z *= inv; acc.w *= inv;
  *(float4*)(Out + (size_t)bk * NC + tid * 4) = acc;
}

extern "C" void kernel_launch(void* const* d_in, const int* in_sizes, int n_in,
                              void* d_out, int out_size, void* d_ws, size_t ws_size,
                              hipStream_t stream) {
  const float* X  = (const float*)d_in[0];
  const int*   Mk = (const int*)d_in[1];
  const float* Q  = (const float*)d_in[2];
  float* Out = (float*)d_out;

  float* Op  = (float*)d_ws;                       // 256*16*1024 f32 = 16 MB
  float* MSp = Op + (size_t)256 * NK * NC;         // 8192 f32
  unsigned short* Qh = (unsigned short*)(MSp + 8192);
  unsigned short* Ql = Qh + NK * NC;

  qprep<<<16, 256, 0, stream>>>(Q, Qh, Ql);
  qpool_partial<<<256, 512, 0, stream>>>(X, Mk, Qh, Ql, Op, MSp);
  qpool_combine<<<256, 256, 0, stream>>>(Op, MSp, Out);
}

// Round 8
// 386.270 us; speedup vs baseline: 2.3392x; 2.3339x over previous
//
#include <hip/hip_runtime.h>
#include <float.h>

// QueryPooling: x[B,L,C] f32, mask[B,L] i32, queries[K,C] f32 -> out[B,K,C] f32
// B=16 L=4096 C=1024 K=16. scale = C^-0.5 = 1/32.
#define NB 16
#define NL 4096
#define NC 1024
#define NK 16
#define SC2 0.04508422f  // (1/32)*log2(e)

typedef __attribute__((ext_vector_type(8))) short bf16x8;
typedef __attribute__((ext_vector_type(4))) float f32x4;

__device__ __forceinline__ float4 ld4(const float* p) { return *(const float4*)p; }

// async global->LDS, 16B/lane. LDS dest must be wave-uniform base (+lane*16 HW).
__device__ __forceinline__ void gload16(const float* g, float* l) {
  __builtin_amdgcn_global_load_lds(
      (const __attribute__((address_space(1))) void*)g,
      (__attribute__((address_space(3))) void*)l, 16, 0, 0);
}

__device__ __forceinline__ void barrier_raw() {
  asm volatile("" ::: "memory");
  __builtin_amdgcn_s_barrier();
  asm volatile("" ::: "memory");
}

// f32 -> (bf16 hi, bf16 lo) RNE split
__device__ __forceinline__ void bf16split(float x, unsigned& h, unsigned& l) {
  union { float f; unsigned v; } z; z.f = x;
  const unsigned rr = z.v + 0x7FFFu + ((z.v >> 16) & 1u);
  h = rr >> 16;
  union { unsigned v; float f; } hf; hf.v = rr & 0xFFFF0000u;
  union { float f; unsigned v; } z2; z2.f = x - hf.f;
  l = (z2.v + 0x7FFFu + ((z2.v >> 16) & 1u)) >> 16;
}

// ---------------------------------------------------------------------------
// Kernel 0: Q[16][1024] f32 -> Qh/Ql bf16 (hi/lo split)
// ---------------------------------------------------------------------------
__global__ void qprep(const float* __restrict__ Q, unsigned short* __restrict__ Qh,
                      unsigned short* __restrict__ Ql) {
  const int i = (blockIdx.x * 256 + threadIdx.x) * 4;
  const float4 q = ld4(Q + i);
  const float qa[4] = {q.x, q.y, q.z, q.w};
  unsigned hh[4], ll[4];
#pragma unroll
  for (int u = 0; u < 4; ++u) bf16split(qa[u], hh[u], ll[u]);
  uint2 ph, pl;
  ph.x = hh[0] | (hh[1] << 16); ph.y = hh[2] | (hh[3] << 16);
  pl.x = ll[0] | (ll[1] << 16); pl.y = ll[2] | (ll[3] << 16);
  *(uint2*)(Qh + i) = ph;
  *(uint2*)(Ql + i) = pl;
}

// ---------------------------------------------------------------------------
// Kernel 1. R8 RESTRUCTURE: kill the VGPR spill under the hard 128-cap
// (empirical: 512-thread blocks always get VGPR<=128 on this toolchain,
// regardless of __launch_bounds__ 2nd arg; R4/R7 showed 1.5+GB scratch).
//  - X staged f32 DIRECTLY to LDS via global_load_lds (no staging regs),
//    double-buffered, counted vmcnt(8) (verified R2 pattern).
//  - f32->bf16 hi/lo conversion moved into phase [2], per wave on its own
//    disjoint K-slice (same total work, ~25 transient regs).
//  - PV reads exact f32 from LDS; W/alpha via LDS broadcast (no 16-reg arrays).
//  - Phase [3] softmax: wave 0 only (Sp traffic /8).
// Register demand ~110 < 128 -> no spill.
// LDS: Xf[2][16][1028] f32 (128.5KB) + Sp 8KB + Wl 1KB + misc ~ 139KB.
// grid 256 (1 block/CU), 512 threads (8 waves). Slab=256 rows, 16 tiles.
// ---------------------------------------------------------------------------
__global__ __launch_bounds__(512, 1)
void qpool_partial(const float* __restrict__ X, const int* __restrict__ Mk,
                   const unsigned short* __restrict__ Qhg,
                   const unsigned short* __restrict__ Qlg,
                   float* __restrict__ Op, float* __restrict__ MSp) {
  constexpr int ROWS = 256;
  constexpr int NT   = 16;
  constexpr int LDF  = 1028;   // f32 row stride (pad 4): frag-read quads uniform

  __shared__ float Xf[2][16 * LDF];
  __shared__ float Sp[8 * 256];   // [w][r16*16 + g*4] b128 (R2/R4 layout)
  __shared__ float Wl[256];       // [r][q]
  __shared__ float aS[16];
  __shared__ int   Msl[ROWS];

  const int tid  = threadIdx.x;
  const int lane = tid & 63;
  const int w    = tid >> 6;
  const int r16  = lane & 15;
  const int g    = lane >> 4;
  const int blk  = blockIdx.x;
  const int b    = blk >> 4;
  const int l0   = (blk & 15) * ROWS;

  const float* Xb = X + (size_t)b * NL * NC + (size_t)l0 * NC;

  // staging decomposition: load j (0..7) -> row j*2+(w>>2), quarter (w&3)
  const int srow = w >> 2;          // row offset parity
  const int squt = (w & 3) * 256;   // f32 column base of this wave's quarter

  // ---- prologue: issue tile-0 staging (8 gload16/thread, no dest regs) ----
#pragma unroll
  for (int j = 0; j < 8; ++j) {
    const int r = j * 2 + srow;
    gload16(Xb + (size_t)r * NC + squt + lane * 4, &Xf[0][r * LDF + squt]);
  }

  // ---- Q fragments (wave w owns K-steps w*4..w*4+3): 32 VGPR ----
  bf16x8 qfh[4], qfl[4];
#pragma unroll
  for (int s = 0; s < 4; ++s) {
    const int off = r16 * NC + (w * 4 + s) * 32 + g * 8;
    qfh[s] = *(const bf16x8*)(Qhg + off);
    qfl[s] = *(const bf16x8*)(Qlg + off);
  }

  if (tid < ROWS) Msl[tid] = Mk[(size_t)b * NL + l0 + tid];

  float o0[16], o1[16];
#pragma unroll
  for (int q = 0; q < 16; ++q) { o0[q] = 0.f; o1[q] = 0.f; }
  float m_run[4], s_run[4];
#pragma unroll
  for (int j = 0; j < 4; ++j) { m_run[j] = -FLT_MAX; s_run[j] = 0.f; }

  for (int t = 0; t < NT; ++t) {
    const int buf = t & 1;
    const float* Xc = &Xf[buf][0];

    barrier_raw();                      // A: prev PV done reading buf^1
    if (t + 1 < NT) {
      const float* Xn = Xb + (size_t)(t + 1) * 16 * NC;
#pragma unroll
      for (int j = 0; j < 8; ++j) {
        const int r = j * 2 + srow;
        gload16(Xn + (size_t)r * NC + squt + lane * 4, &Xf[buf ^ 1][r * LDF + squt]);
      }
      asm volatile("s_waitcnt vmcnt(8)" ::: "memory");  // buf landed, next 8 fly
    } else {
      asm volatile("s_waitcnt vmcnt(0)" ::: "memory");
    }
    barrier_raw();                      // B: buf fully staged

    // [2] scores: convert this wave's K-slice f32->bf16 hi/lo, 3-MFMA split
    f32x4 sacc = {0.f, 0.f, 0.f, 0.f};
#pragma unroll
    for (int s = 0; s < 4; ++s) {
      const float* rp = &Xc[r16 * LDF + w * 128 + s * 32 + g * 8];
      const f32x4 xa = *(const f32x4*)rp;
      const f32x4 xb2 = *(const f32x4*)(rp + 4);
      bf16x8 xh, xl;
#pragma unroll
      for (int u = 0; u < 4; ++u) {
        unsigned h, l;
        bf16split(xa[u], h, l);
        xh[u] = (short)h; xl[u] = (short)l;
        bf16split(xb2[u], h, l);
        xh[4 + u] = (short)h; xl[4 + u] = (short)l;
      }
      sacc = __builtin_amdgcn_mfma_f32_16x16x32_bf16(qfh[s], xh, sacc, 0, 0, 0);
      sacc = __builtin_amdgcn_mfma_f32_16x16x32_bf16(qfh[s], xl, sacc, 0, 0, 0);
      sacc = __builtin_amdgcn_mfma_f32_16x16x32_bf16(qfl[s], xh, sacc, 0, 0, 0);
    }
    *(f32x4*)&Sp[w * 256 + r16 * 16 + g * 4] = sacc;
    asm volatile("s_waitcnt lgkmcnt(0)" ::: "memory");
    barrier_raw();                      // B2: partials visible

    // [3] wave 0 only: reduce over waves + online softmax -> Wl, aS
    if (w == 0) {
      float sred[4] = {0.f, 0.f, 0.f, 0.f};
#pragma unroll
      for (int ww = 0; ww < 8; ++ww) {
        const f32x4 p = *(const f32x4*)&Sp[ww * 256 + r16 * 16 + g * 4];
        sred[0] += p[0]; sred[1] += p[1]; sred[2] += p[2]; sred[3] += p[3];
      }
      const int mskr = Msl[t * 16 + r16];
      float e4[4], al4[4];
#pragma unroll
      for (int j = 0; j < 4; ++j) {
        float mx = mskr ? sred[j] : -FLT_MAX;
        mx = fmaxf(mx, __shfl_xor(mx, 1, 64));
        mx = fmaxf(mx, __shfl_xor(mx, 2, 64));
        mx = fmaxf(mx, __shfl_xor(mx, 4, 64));
        mx = fmaxf(mx, __shfl_xor(mx, 8, 64));
        const float mnew = fmaxf(m_run[j], mx);
        const float e = mskr ? exp2f((sred[j] - mnew) * SC2) : 0.f;
        float cs = e;
        cs += __shfl_xor(cs, 1, 64);
        cs += __shfl_xor(cs, 2, 64);
        cs += __shfl_xor(cs, 4, 64);
        cs += __shfl_xor(cs, 8, 64);
        al4[j] = exp2f((m_run[j] - mnew) * SC2);   // ==1 when unchanged
        s_run[j] = s_run[j] * al4[j] + cs;
        m_run[j] = mnew;
        e4[j] = e;
      }
      *(float4*)&Wl[r16 * 16 + g * 4] = make_float4(e4[0], e4[1], e4[2], e4[3]);
      if (r16 == 0) *(float4*)&aS[g * 4] = make_float4(al4[0], al4[1], al4[2], al4[3]);
    }
    asm volatile("s_waitcnt lgkmcnt(0)" ::: "memory");
    barrier_raw();                      // C: Wl/aS visible

    // [4] rescale (aS broadcast) + PV on exact f32 (wave w: cols w*128..+128)
    const int c0 = w * 128 + lane * 2;
#pragma unroll
    for (int q = 0; q < 16; ++q) {
      const float a = aS[q];
      o0[q] *= a; o1[q] *= a;
    }
#pragma unroll
    for (int r = 0; r < 16; ++r) {
      const float2 xv = *(const float2*)&Xc[r * LDF + c0];
#pragma unroll
      for (int qq = 0; qq < 4; ++qq) {
        const f32x4 wv = *(const f32x4*)&Wl[r * 16 + qq * 4];
#pragma unroll
        for (int u = 0; u < 4; ++u) {
          o0[qq * 4 + u] = fmaf(wv[u], xv.x, o0[qq * 4 + u]);
          o1[qq * 4 + u] = fmaf(wv[u], xv.y, o1[qq * 4 + u]);
        }
      }
    }
  }

  // ---- epilogue: slab partials ----
  float* Ob = Op + (size_t)blk * NK * NC;
  const int c0 = w * 128 + lane * 2;
#pragma unroll
  for (int q = 0; q < 16; ++q)
    *(float2*)(Ob + (size_t)q * NC + c0) = make_float2(o0[q], o1[q]);
  if (w == 0 && r16 == 0) {
#pragma unroll
    for (int j = 0; j < 4; ++j) {
      const int q = g * 4 + j;
      MSp[(blk * 16 + q) * 2]     = m_run[j];
      MSp[(blk * 16 + q) * 2 + 1] = s_run[j];
    }
  }
}

// ---------------------------------------------------------------------------
// Kernel 2: merge 16 slab partials per (b,k), max-rescale + normalize.
// All-masked batch -> denom 0 -> zeros (matches reference valid-branch).
// ---------------------------------------------------------------------------
__global__ __launch_bounds__(256, 1)
void qpool_combine(const float* __restrict__ Op, const float* __restrict__ MSp,
                   float* __restrict__ Out) {
  const int bk = blockIdx.x;
  const int b = bk >> 4, k = bk & 15;
  const int tid = threadIdx.x;

  float m[16], s[16], f[16];
  float M = -FLT_MAX;
#pragma unroll
  for (int lb = 0; lb < 16; ++lb) {
    m[lb] = MSp[((b * 16 + lb) * 16 + k) * 2];
    s[lb] = MSp[((b * 16 + lb) * 16 + k) * 2 + 1];
    M = fmaxf(M, m[lb]);
  }
  float denom = 0.f;
#pragma unroll
  for (int lb = 0; lb < 16; ++lb) {
    f[lb] = exp2f((m[lb] - M) * SC2);
    denom += s[lb] * f[lb];
  }
  float4 acc = make_float4(0.f, 0.f, 0.f, 0.f);
#pragma unroll
  for (int lb = 0; lb < 16; ++lb) {
    const float4 v = ld4(Op + ((size_t)(b * 16 + lb) * 16 + k) * NC + tid * 4);
    acc.x = fmaf(f[lb], v.x, acc.x);
    acc.y = fmaf(f[lb], v.y, acc.y);
    acc.z = fmaf(f[lb], v.z, acc.z);
    acc.w = fmaf(f[lb], v.w, acc.w);
  }
  const float inv = denom > 0.f ? 1.f / denom : 0.f;
  acc.x *= inv; acc.y *= inv; acc.z *= inv; acc.w *= inv;
  *(float4*)(Out + (size_t)bk * NC + tid * 4) = acc;
}

extern "C" void kernel_launch(void* const* d_in, const int* in_sizes, int n_in,
                              void* d_out, int out_size, void* d_ws, size_t ws_size,
                              hipStream_t stream) {
  const float* X  = (const float*)d_in[0];
  const int*   Mk = (const int*)d_in[1];
  const float* Q  = (const float*)d_in[2];
  float* Out = (float*)d_out;

  float* Op  = (float*)d_ws;                       // 256*16*1024 f32 = 16 MB
  float* MSp = Op + (size_t)256 * NK * NC;         // 8192 f32
  unsigned short* Qh = (unsigned short*)(MSp + 8192);
  unsigned short* Ql = Qh + NK * NC;

  qprep<<<16, 256, 0, stream>>>(Q, Qh, Ql);
  qpool_partial<<<256, 512, 0, stream>>>(X, Mk, Qh, Ql, Op, MSp);
  qpool_combine<<<256, 256, 0, stream>>>(Op, MSp, Out);
}